// Round 2
// baseline (80.431 us; speedup 1.0000x reference)
//
#include <hip/hip_runtime.h>

// Probabilistic Conway forward prop.
// in:  (32, 1024, 1024) float32 live-probabilities
// out: (32, 1024, 1024) float32 = pmf3 + pmf2 * p_self
// where pmf_k is the Poisson-binomial pmf over the 8 Moore neighbors
// (torus wrap), computed with the DP recurrence truncated at k=3.

#define H 1024
#define W 1024

__global__ __launch_bounds__(256) void prob_conway_kernel(
    const float* __restrict__ in, float* __restrict__ out) {
    // One block per (plane, row); each thread does 4 consecutive columns.
    const int cq = threadIdx.x;            // 0..255 -> col quad
    const int r  = blockIdx.x & (H - 1);   // row
    const int p  = blockIdx.x >> 10;       // plane

    const float* __restrict__ img = in + (size_t)p * (H * W);
    float* __restrict__ o         = out + (size_t)p * (H * W);

    const int c0 = cq * 4;
    const int rm = (r + H - 1) & (H - 1);
    const int rp = (r + 1) & (H - 1);
    const int cl = (c0 + W - 1) & (W - 1);
    const int cr = (c0 + 4) & (W - 1);

    const float* rowT = img + (size_t)rm * W;
    const float* rowM = img + (size_t)r  * W;
    const float* rowB = img + (size_t)rp * W;

    const float4 vT = *reinterpret_cast<const float4*>(rowT + c0);
    const float4 vM = *reinterpret_cast<const float4*>(rowM + c0);
    const float4 vB = *reinterpret_cast<const float4*>(rowB + c0);
    const float lT = rowT[cl], rT = rowT[cr];
    const float lM = rowM[cl], rM = rowM[cr];
    const float lB = rowB[cl], rB = rowB[cr];

    const float top[6] = {lT, vT.x, vT.y, vT.z, vT.w, rT};
    const float mid[6] = {lM, vM.x, vM.y, vM.z, vM.w, rM};
    const float bot[6] = {lB, vB.x, vB.y, vB.z, vB.w, rB};

    float res[4];
#pragma unroll
    for (int j = 0; j < 4; ++j) {
        const float nbr[8] = {
            top[j], top[j + 1], top[j + 2],
            mid[j],             mid[j + 2],
            bot[j], bot[j + 1], bot[j + 2]
        };
        float pmf0 = 1.0f, pmf1 = 0.0f, pmf2 = 0.0f, pmf3 = 0.0f;
#pragma unroll
        for (int k = 0; k < 8; ++k) {
            const float pv = nbr[k];
            const float qv = 1.0f - pv;
            pmf3 = pmf3 * qv + pmf2 * pv;
            pmf2 = pmf2 * qv + pmf1 * pv;
            pmf1 = pmf1 * qv + pmf0 * pv;
            pmf0 = pmf0 * qv;
        }
        res[j] = pmf3 + pmf2 * mid[j + 1];
    }

    float4 rv;
    rv.x = res[0]; rv.y = res[1]; rv.z = res[2]; rv.w = res[3];
    // BUG FIX vs round 1: store must include the row offset (was `o + c0`,
    // which wrote every row to plane-row-0 and left the rest zeros).
    *reinterpret_cast<float4*>(o + (size_t)r * W + c0) = rv;
}

extern "C" void kernel_launch(void* const* d_in, const int* in_sizes, int n_in,
                              void* d_out, int out_size, void* d_ws, size_t ws_size,
                              hipStream_t stream) {
    const float* in = (const float*)d_in[0];
    float* out = (float*)d_out;
    // 32 planes * 1024 rows = 32768 blocks, 256 threads each (4 cols/thread)
    dim3 grid(32 * H);
    dim3 block(256);
    prob_conway_kernel<<<grid, block, 0, stream>>>(in, out);
}

// Round 3
// 57.914 us; speedup vs baseline: 1.3888x; 1.3888x over previous
//
#include <hip/hip_runtime.h>

// Probabilistic Conway forward prop.
// in:  (32, 1024, 1024) float32 live-probabilities
// out: (32, 1024, 1024) float32 = pmf3 + pmf2 * p_self
// pmf_k = Poisson-binomial pmf over the 8 Moore neighbors (torus wrap),
// DP recurrence truncated at k=3.
//
// Round 3: (a) XCD-aware block swizzle so adjacent row-groups share an XCD L2
// (FETCH was 1.5x ideal: row reuse missed across XCDs); (b) 4 rows per thread
// with all 6 input rows held in registers (compile-time indexing only) to cut
// VMEM instructions per cell 2x and in-kernel vertical re-reads 3x -> 1.5x.

#define H 1024
#define W 1024
#define RPT 4  // output rows per thread

__global__ __launch_bounds__(256) void prob_conway_kernel(
    const float* __restrict__ in, float* __restrict__ out) {
    // Grid: 32 planes * (1024/RPT) row-groups = 8192 blocks.
    // XCD swizzle (bijective: 8192 % 8 == 0): blocks with bid%8==x are
    // dispatched to XCD x (round-robin assumption); give each XCD a
    // contiguous chunk of the spatial index so vertical neighbors share L2.
    const int nblk = 32 * (H / RPT);       // 8192
    const int cpx  = nblk / 8;             // 1024
    const int bid  = blockIdx.x;
    const int s    = (bid & 7) * cpx + (bid >> 3);

    const int plane = s >> 8;              // 256 row-groups per plane
    const int rg    = s & 255;
    const int r0    = rg * RPT;
    const int c0    = threadIdx.x * 4;     // 256 threads cover 1024 cols

    const float* __restrict__ img = in + (size_t)plane * (H * W);
    float* __restrict__ o         = out + (size_t)plane * (H * W);

    const int cl = (c0 + W - 1) & (W - 1);
    const int cr = (c0 + 4) & (W - 1);

    // Load the RPT+2 = 6 input rows this thread needs: cols [c0-1 .. c0+4].
    float P[RPT + 2][6];
#pragma unroll
    for (int i = 0; i < RPT + 2; ++i) {
        const int r = (r0 + i - 1 + H) & (H - 1);
        const float* row = img + (size_t)r * W;
        const float4 v = *reinterpret_cast<const float4*>(row + c0);
        P[i][0] = row[cl];
        P[i][1] = v.x; P[i][2] = v.y; P[i][3] = v.z; P[i][4] = v.w;
        P[i][5] = row[cr];
    }

#pragma unroll
    for (int i = 0; i < RPT; ++i) {
        float res[4];
#pragma unroll
        for (int j = 0; j < 4; ++j) {
            const float nbr[8] = {
                P[i][j],     P[i][j + 1],     P[i][j + 2],
                P[i + 1][j],                  P[i + 1][j + 2],
                P[i + 2][j], P[i + 2][j + 1], P[i + 2][j + 2]
            };
            float pmf0 = 1.0f, pmf1 = 0.0f, pmf2 = 0.0f, pmf3 = 0.0f;
#pragma unroll
            for (int k = 0; k < 8; ++k) {
                const float pv = nbr[k];
                const float qv = 1.0f - pv;
                pmf3 = pmf3 * qv + pmf2 * pv;
                pmf2 = pmf2 * qv + pmf1 * pv;
                pmf1 = pmf1 * qv + pmf0 * pv;
                pmf0 = pmf0 * qv;
            }
            res[j] = pmf3 + pmf2 * P[i + 1][j + 1];
        }
        float4 rv;
        rv.x = res[0]; rv.y = res[1]; rv.z = res[2]; rv.w = res[3];
        *reinterpret_cast<float4*>(o + (size_t)(r0 + i) * W + c0) = rv;
    }
}

extern "C" void kernel_launch(void* const* d_in, const int* in_sizes, int n_in,
                              void* d_out, int out_size, void* d_ws, size_t ws_size,
                              hipStream_t stream) {
    const float* in = (const float*)d_in[0];
    float* out = (float*)d_out;
    dim3 grid(32 * (H / RPT));   // 8192 blocks
    dim3 block(256);
    prob_conway_kernel<<<grid, block, 0, stream>>>(in, out);
}

// Round 4
// 53.910 us; speedup vs baseline: 1.4919x; 1.0743x over previous
//
#include <hip/hip_runtime.h>

// Probabilistic Conway forward prop.
// in:  (32, 1024, 1024) float32; out = pmf3 + pmf2 * p_self over 8 Moore
// neighbors (torus), Poisson-binomial DP truncated at k=3.
//
// Round 4: RPT=8 (vertical redundancy 1.25x), halo via __shfl from
// neighbor lanes; wave-edge halos (2 cols x 10 rows = 20 values) fetched by
// ONE gather load on lanes 0..19 and distributed by shfl. Cuts VMEM
// instructions per cell ~2.3x vs round 3 (scalar halo loads were ~55% of
// load-issue cycles). XCD-aware swizzle retained (4096 % 8 == 0).

#define H 1024
#define W 1024
#define RPT 8
#define NROWS (RPT + 2)

__global__ __launch_bounds__(256) void prob_conway_kernel(
    const float* __restrict__ in, float* __restrict__ out) {
    const int nblk = 32 * (H / RPT);       // 4096
    const int cpx  = nblk / 8;             // 512 blocks per XCD chunk
    const int bid  = blockIdx.x;
    const int s    = (bid & 7) * cpx + (bid >> 3);   // bijective swizzle

    const int plane = s >> 7;              // 128 row-groups per plane
    const int rg    = s & 127;
    const int r0    = rg * RPT;
    const int lane  = threadIdx.x & 63;
    const int c0    = threadIdx.x * 4;     // 256 threads cover 1024 cols

    const float* __restrict__ img = in + (size_t)plane * (H * W);
    float* __restrict__ o         = out + (size_t)plane * (H * W);

    // ---- vector loads: 10 rows x float4 ----
    float P[NROWS][6];
#pragma unroll
    for (int i = 0; i < NROWS; ++i) {
        const int r = (r0 + i - 1 + H) & (H - 1);
        const float4 v = *reinterpret_cast<const float4*>(img + (size_t)r * W + c0);
        P[i][1] = v.x; P[i][2] = v.y; P[i][3] = v.z; P[i][4] = v.w;
    }

    // ---- one gather load fetches all 20 wave-edge halo values ----
    // gather lane 2i   -> row i left  halo (col wbase-1 mod W)
    // gather lane 2i+1 -> row i right halo (col wbase+256 mod W)
    const int wbase = (threadIdx.x >> 6) << 8;         // wave base col
    const int clw   = (wbase + W - 1) & (W - 1);
    const int crw   = (wbase + 256) & (W - 1);
    int gi = lane >> 1;
    gi = (gi < NROWS) ? gi : 0;                        // lanes >=20 duplicate
    const int grow = (r0 + gi - 1 + H) & (H - 1);
    const int gcol = (lane & 1) ? crw : clw;
    const float gv = img[(size_t)grow * W + gcol];

    // ---- distribute halos: interior via shfl, wave edges via gather ----
#pragma unroll
    for (int i = 0; i < NROWS; ++i) {
        const float lv = __shfl_up(P[i][4], 1);        // lane-1's v.w
        const float rv = __shfl_down(P[i][1], 1);      // lane+1's v.x
        const float e  = __shfl(gv, 2 * i + ((lane == 63) ? 1 : 0));
        P[i][0] = (lane == 0)  ? e : lv;
        P[i][5] = (lane == 63) ? e : rv;
    }

    // ---- DP per output row ----
#pragma unroll
    for (int j = 0; j < RPT; ++j) {
        float res[4];
#pragma unroll
        for (int x = 0; x < 4; ++x) {
            const float nbr[8] = {
                P[j][x],     P[j][x + 1],     P[j][x + 2],
                P[j + 1][x],                  P[j + 1][x + 2],
                P[j + 2][x], P[j + 2][x + 1], P[j + 2][x + 2]
            };
            float pmf0 = 1.0f, pmf1 = 0.0f, pmf2 = 0.0f, pmf3 = 0.0f;
#pragma unroll
            for (int k = 0; k < 8; ++k) {
                const float pv = nbr[k];
                const float qv = 1.0f - pv;
                pmf3 = pmf3 * qv + pmf2 * pv;
                pmf2 = pmf2 * qv + pmf1 * pv;
                pmf1 = pmf1 * qv + pmf0 * pv;
                pmf0 = pmf0 * qv;
            }
            res[x] = pmf3 + pmf2 * P[j + 1][x + 1];
        }
        float4 rv4;
        rv4.x = res[0]; rv4.y = res[1]; rv4.z = res[2]; rv4.w = res[3];
        *reinterpret_cast<float4*>(o + (size_t)(r0 + j) * W + c0) = rv4;
    }
}

extern "C" void kernel_launch(void* const* d_in, const int* in_sizes, int n_in,
                              void* d_out, int out_size, void* d_ws, size_t ws_size,
                              hipStream_t stream) {
    const float* in = (const float*)d_in[0];
    float* out = (float*)d_out;
    dim3 grid(32 * (H / RPT));   // 4096 blocks
    dim3 block(256);
    prob_conway_kernel<<<grid, block, 0, stream>>>(in, out);
}

// Round 5
// 51.997 us; speedup vs baseline: 1.5468x; 1.0368x over previous
//
#include <hip/hip_runtime.h>

// Probabilistic Conway forward prop.
// in:  (32, 1024, 1024) float32; out = pmf3 + pmf2 * p_self over 8 Moore
// neighbors (torus), Poisson-binomial pmf truncated at k=3.
//
// Round 5: FACTORIZED pmf. The 8-neighbor generating polynomial factors by
// column:  Phi(r,c) = V3(c-1) * D(c) * V3(c+1)
//   V3(col) = product over 3-row vertical window (degree-3 poly, 4 coeffs)
//   D(col)  = product over {top,bot} pair, center excluded (degree-2, 3 coeffs)
// Column polys are computed once per (row,col) and shared by up to 3 outputs.
// Cuts VALU ops/cell ~65 -> ~30 (VALU-issue was ~half the wall in round 4).
// Truncating every product at degree 3 is exact for pmf2/pmf3 (nonneg coeffs,
// high coeffs never feed low ones). RPT=8, shfl halos, XCD swizzle retained.

#define H 1024
#define W 1024
#define RPT 8
#define NROWS (RPT + 2)

__global__ __launch_bounds__(256) void prob_conway_kernel(
    const float* __restrict__ in, float* __restrict__ out) {
    const int nblk = 32 * (H / RPT);       // 4096
    const int cpx  = nblk / 8;             // 512 blocks per XCD chunk
    const int bid  = blockIdx.x;
    const int s    = (bid & 7) * cpx + (bid >> 3);   // bijective swizzle

    const int plane = s >> 7;              // 128 row-groups per plane
    const int rg    = s & 127;
    const int r0    = rg * RPT;
    const int lane  = threadIdx.x & 63;
    const int c0    = threadIdx.x * 4;     // 256 threads cover 1024 cols

    const float* __restrict__ img = in + (size_t)plane * (H * W);
    float* __restrict__ o         = out + (size_t)plane * (H * W);

    // ---- vector loads: 10 rows x float4 ----
    float P[NROWS][6];
#pragma unroll
    for (int i = 0; i < NROWS; ++i) {
        const int r = (r0 + i - 1 + H) & (H - 1);
        const float4 v = *reinterpret_cast<const float4*>(img + (size_t)r * W + c0);
        P[i][1] = v.x; P[i][2] = v.y; P[i][3] = v.z; P[i][4] = v.w;
    }

    // ---- one gather load fetches all 20 wave-edge halo values ----
    const int wbase = (threadIdx.x >> 6) << 8;         // wave base col
    const int clw   = (wbase + W - 1) & (W - 1);
    const int crw   = (wbase + 256) & (W - 1);
    int gi = lane >> 1;
    gi = (gi < NROWS) ? gi : 0;                        // lanes >=20 duplicate
    const int grow = (r0 + gi - 1 + H) & (H - 1);
    const int gcol = (lane & 1) ? crw : clw;
    const float gv = img[(size_t)grow * W + gcol];

    // ---- distribute halos: interior via shfl, wave edges via gather ----
#pragma unroll
    for (int i = 0; i < NROWS; ++i) {
        const float lv = __shfl_up(P[i][4], 1);        // lane-1's v.w
        const float rv = __shfl_down(P[i][1], 1);      // lane+1's v.x
        const float e  = __shfl(gv, 2 * i + ((lane == 63) ? 1 : 0));
        P[i][0] = (lane == 0)  ? e : lv;
        P[i][5] = (lane == 63) ? e : rv;
    }

    // ---- factorized pmf per output row ----
#pragma unroll
    for (int j = 0; j < RPT; ++j) {
        // Column polynomials for the 3-row window centered at output row j.
        float v3[6][4];   // V3 per column (cols c0-1 .. c0+4)
        float dd[4][3];   // pair poly per center column (cols c0 .. c0+3)
#pragma unroll
        for (int jc = 0; jc < 6; ++jc) {
            const float a  = P[j][jc];          // top
            const float b  = P[j + 1][jc];      // mid
            const float cc = P[j + 2][jc];      // bot
            const float qa = 1.0f - a, qb = 1.0f - b, qc = 1.0f - cc;
            // pair {top,bot}: d0 + d1 z + d2 z^2
            const float d0 = qa * qc;
            const float d1 = qa * cc + a * qc;
            const float d2 = a * cc;
            // V3 = pair * (qb + b z)
            v3[jc][0] = d0 * qb;
            v3[jc][1] = d1 * qb + d0 * b;
            v3[jc][2] = d2 * qb + d1 * b;
            v3[jc][3] = d2 * b;
            if (jc >= 1 && jc <= 4) {
                dd[jc - 1][0] = d0; dd[jc - 1][1] = d1; dd[jc - 1][2] = d2;
            }
        }
        float res[4];
#pragma unroll
        for (int x = 0; x < 4; ++x) {
            const float* L = v3[x];
            const float* R = v3[x + 2];
            const float* D = dd[x];
            // W = L (*) R, truncated at degree 3
            const float w0 = L[0] * R[0];
            const float w1 = L[1] * R[0] + L[0] * R[1];
            const float w2 = L[2] * R[0] + L[1] * R[1] + L[0] * R[2];
            const float w3 = L[3] * R[0] + L[2] * R[1] + L[1] * R[2] + L[0] * R[3];
            // pmf2/pmf3 = coeffs of W (*) D
            const float pmf2 = w2 * D[0] + w1 * D[1] + w0 * D[2];
            const float pmf3 = w3 * D[0] + w2 * D[1] + w1 * D[2];
            res[x] = pmf3 + pmf2 * P[j + 1][x + 1];
        }
        float4 rv4;
        rv4.x = res[0]; rv4.y = res[1]; rv4.z = res[2]; rv4.w = res[3];
        *reinterpret_cast<float4*>(o + (size_t)(r0 + j) * W + c0) = rv4;
    }
}

extern "C" void kernel_launch(void* const* d_in, const int* in_sizes, int n_in,
                              void* d_out, int out_size, void* d_ws, size_t ws_size,
                              hipStream_t stream) {
    const float* in = (const float*)d_in[0];
    float* out = (float*)d_out;
    dim3 grid(32 * (H / RPT));   // 4096 blocks
    dim3 block(256);
    prob_conway_kernel<<<grid, block, 0, stream>>>(in, out);
}

// Round 7
// 48.207 us; speedup vs baseline: 1.6684x; 1.0786x over previous
//
#include <hip/hip_runtime.h>

// Probabilistic Conway forward prop.
// in:  (32, 1024, 1024) float32; out = pmf3 + pmf2 * p_self over 8 Moore
// neighbors (torus), Poisson-binomial pmf truncated at k=3.
//
// Round 7: round-6 theory (non-temporal output stores so the write-once
// output stream does not evict the L3-resident input; input+output = 256 MiB
// = exactly the Infinity Cache capacity) with the compile fix:
// __builtin_nontemporal_store requires a NATIVE vector type, not
// HIP_vector_type<float,4> -> use ext_vector_type(4) float.
// Factorized column-polynomial pmf (round 5), RPT=8, shfl halos, XCD swizzle.

#define H 1024
#define W 1024
#define RPT 8
#define NROWS (RPT + 2)

typedef float f32x4 __attribute__((ext_vector_type(4)));

__global__ __launch_bounds__(256) void prob_conway_kernel(
    const float* __restrict__ in, float* __restrict__ out) {
    const int nblk = 32 * (H / RPT);       // 4096
    const int cpx  = nblk / 8;             // 512 blocks per XCD chunk
    const int bid  = blockIdx.x;
    const int s    = (bid & 7) * cpx + (bid >> 3);   // bijective swizzle

    const int plane = s >> 7;              // 128 row-groups per plane
    const int rg    = s & 127;
    const int r0    = rg * RPT;
    const int lane  = threadIdx.x & 63;
    const int c0    = threadIdx.x * 4;     // 256 threads cover 1024 cols

    const float* __restrict__ img = in + (size_t)plane * (H * W);
    float* __restrict__ o         = out + (size_t)plane * (H * W);

    // ---- vector loads: 10 rows x float4 ----
    float P[NROWS][6];
#pragma unroll
    for (int i = 0; i < NROWS; ++i) {
        const int r = (r0 + i - 1 + H) & (H - 1);
        const f32x4 v = *reinterpret_cast<const f32x4*>(img + (size_t)r * W + c0);
        P[i][1] = v.x; P[i][2] = v.y; P[i][3] = v.z; P[i][4] = v.w;
    }

    // ---- one gather load fetches all 20 wave-edge halo values ----
    const int wbase = (threadIdx.x >> 6) << 8;         // wave base col
    const int clw   = (wbase + W - 1) & (W - 1);
    const int crw   = (wbase + 256) & (W - 1);
    int gi = lane >> 1;
    gi = (gi < NROWS) ? gi : 0;                        // lanes >=20 duplicate
    const int grow = (r0 + gi - 1 + H) & (H - 1);
    const int gcol = (lane & 1) ? crw : clw;
    const float gv = img[(size_t)grow * W + gcol];

    // ---- distribute halos: interior via shfl, wave edges via gather ----
#pragma unroll
    for (int i = 0; i < NROWS; ++i) {
        const float lv = __shfl_up(P[i][4], 1);        // lane-1's v.w
        const float rv = __shfl_down(P[i][1], 1);      // lane+1's v.x
        const float e  = __shfl(gv, 2 * i + ((lane == 63) ? 1 : 0));
        P[i][0] = (lane == 0)  ? e : lv;
        P[i][5] = (lane == 63) ? e : rv;
    }

    // ---- factorized pmf per output row ----
#pragma unroll
    for (int j = 0; j < RPT; ++j) {
        // Column polynomials for the 3-row window centered at output row j.
        float v3[6][4];   // V3 per column (cols c0-1 .. c0+4)
        float dd[4][3];   // pair poly per center column (cols c0 .. c0+3)
#pragma unroll
        for (int jc = 0; jc < 6; ++jc) {
            const float a  = P[j][jc];          // top
            const float b  = P[j + 1][jc];      // mid
            const float cc = P[j + 2][jc];      // bot
            const float qa = 1.0f - a, qb = 1.0f - b, qc = 1.0f - cc;
            // pair {top,bot}: d0 + d1 z + d2 z^2
            const float d0 = qa * qc;
            const float d1 = qa * cc + a * qc;
            const float d2 = a * cc;
            // V3 = pair * (qb + b z)
            v3[jc][0] = d0 * qb;
            v3[jc][1] = d1 * qb + d0 * b;
            v3[jc][2] = d2 * qb + d1 * b;
            v3[jc][3] = d2 * b;
            if (jc >= 1 && jc <= 4) {
                dd[jc - 1][0] = d0; dd[jc - 1][1] = d1; dd[jc - 1][2] = d2;
            }
        }
        f32x4 rv4;
#pragma unroll
        for (int x = 0; x < 4; ++x) {
            const float* L = v3[x];
            const float* R = v3[x + 2];
            const float* D = dd[x];
            // W = L (*) R, truncated at degree 3
            const float w0 = L[0] * R[0];
            const float w1 = L[1] * R[0] + L[0] * R[1];
            const float w2 = L[2] * R[0] + L[1] * R[1] + L[0] * R[2];
            const float w3 = L[3] * R[0] + L[2] * R[1] + L[1] * R[2] + L[0] * R[3];
            // pmf2/pmf3 = coeffs of W (*) D
            const float pmf2 = w2 * D[0] + w1 * D[1] + w0 * D[2];
            const float pmf3 = w3 * D[0] + w2 * D[1] + w1 * D[2];
            rv4[x] = pmf3 + pmf2 * P[j + 1][x + 1];
        }
        // Non-temporal: output is write-once; don't let it evict the input
        // from L2/L3 (input+output = 256 MiB = exactly L3 capacity).
        __builtin_nontemporal_store(
            rv4, reinterpret_cast<f32x4*>(o + (size_t)(r0 + j) * W + c0));
    }
}

extern "C" void kernel_launch(void* const* d_in, const int* in_sizes, int n_in,
                              void* d_out, int out_size, void* d_ws, size_t ws_size,
                              hipStream_t stream) {
    const float* in = (const float*)d_in[0];
    float* out = (float*)d_out;
    dim3 grid(32 * (H / RPT));   // 4096 blocks
    dim3 block(256);
    prob_conway_kernel<<<grid, block, 0, stream>>>(in, out);
}

// Round 9
// 45.757 us; speedup vs baseline: 1.7578x; 1.0536x over previous
//
#include <hip/hip_runtime.h>

// Probabilistic Conway forward prop.
// in:  (32, 1024, 1024) float32; out = pmf3 + pmf2 * p_self over 8 Moore
// neighbors (torus), Poisson-binomial pmf truncated at k=3.
//
// Round 9: revert round-8's sc1/nt inline-asm store (coherence hazard: it
// bypassed L2 without invalidating stale lines, and inline-asm VMEM isn't in
// the compiler's waitcnt bookkeeping -> validation read stale data). Keep the
// SAFE __builtin_nontemporal_store (round 7, passing) and keep round-8's
// non-wrapping fast-path row addressing (126/128 row-groups: base ptr += W
// instead of per-row wrap masks).
// Factorized column-polynomial pmf (round 5), RPT=8, shfl halos, XCD swizzle.

#define H 1024
#define W 1024
#define RPT 8
#define NROWS (RPT + 2)

typedef float f32x4 __attribute__((ext_vector_type(4)));

__global__ __launch_bounds__(256) void prob_conway_kernel(
    const float* __restrict__ in, float* __restrict__ out) {
    const int nblk = 32 * (H / RPT);       // 4096
    const int cpx  = nblk / 8;             // 512 blocks per XCD chunk
    const int bid  = blockIdx.x;
    const int s    = (bid & 7) * cpx + (bid >> 3);   // bijective swizzle

    const int plane = s >> 7;              // 128 row-groups per plane
    const int rg    = s & 127;
    const int r0    = rg * RPT;
    const int lane  = threadIdx.x & 63;
    const int c0    = threadIdx.x * 4;     // 256 threads cover 1024 cols

    const float* __restrict__ img = in + (size_t)plane * (H * W);
    float* __restrict__ o         = out + (size_t)plane * (H * W);

    // ---- one gather load fetches all 20 wave-edge halo values ----
    const int wbase = (threadIdx.x >> 6) << 8;         // wave base col
    const int clw   = (wbase + W - 1) & (W - 1);
    const int crw   = (wbase + 256) & (W - 1);
    int gi = lane >> 1;
    gi = (gi < NROWS) ? gi : 0;                        // lanes >=20 duplicate
    const int grow = (r0 + gi - 1 + H) & (H - 1);
    const int gcol = (lane & 1) ? crw : clw;
    const float gv = img[(size_t)grow * W + gcol];

    // ---- vector loads: 10 rows x float4 ----
    float P[NROWS][6];
    if (rg != 0 && rg != 127) {
        // Fast path: rows r0-1 .. r0+8 are contiguous, no vertical wrap.
        const float* rp = img + (size_t)(r0 - 1) * W + c0;
#pragma unroll
        for (int i = 0; i < NROWS; ++i) {
            const f32x4 v = *reinterpret_cast<const f32x4*>(rp);
            P[i][1] = v.x; P[i][2] = v.y; P[i][3] = v.z; P[i][4] = v.w;
            rp += W;
        }
    } else {
#pragma unroll
        for (int i = 0; i < NROWS; ++i) {
            const int r = (r0 + i - 1 + H) & (H - 1);
            const f32x4 v =
                *reinterpret_cast<const f32x4*>(img + (size_t)r * W + c0);
            P[i][1] = v.x; P[i][2] = v.y; P[i][3] = v.z; P[i][4] = v.w;
        }
    }

    // ---- distribute halos: interior via shfl, wave edges via gather ----
#pragma unroll
    for (int i = 0; i < NROWS; ++i) {
        const float lv = __shfl_up(P[i][4], 1);        // lane-1's v.w
        const float rv = __shfl_down(P[i][1], 1);      // lane+1's v.x
        const float e  = __shfl(gv, 2 * i + ((lane == 63) ? 1 : 0));
        P[i][0] = (lane == 0)  ? e : lv;
        P[i][5] = (lane == 63) ? e : rv;
    }

    // ---- factorized pmf per output row ----
#pragma unroll
    for (int j = 0; j < RPT; ++j) {
        // Column polynomials for the 3-row window centered at output row j.
        float v3[6][4];   // V3 per column (cols c0-1 .. c0+4)
        float dd[4][3];   // pair poly per center column (cols c0 .. c0+3)
#pragma unroll
        for (int jc = 0; jc < 6; ++jc) {
            const float a  = P[j][jc];          // top
            const float b  = P[j + 1][jc];      // mid
            const float cc = P[j + 2][jc];      // bot
            const float qa = 1.0f - a, qb = 1.0f - b, qc = 1.0f - cc;
            // pair {top,bot}: d0 + d1 z + d2 z^2
            const float d0 = qa * qc;
            const float d1 = qa * cc + a * qc;
            const float d2 = a * cc;
            // V3 = pair * (qb + b z)
            v3[jc][0] = d0 * qb;
            v3[jc][1] = d1 * qb + d0 * b;
            v3[jc][2] = d2 * qb + d1 * b;
            v3[jc][3] = d2 * b;
            if (jc >= 1 && jc <= 4) {
                dd[jc - 1][0] = d0; dd[jc - 1][1] = d1; dd[jc - 1][2] = d2;
            }
        }
        f32x4 rv4;
#pragma unroll
        for (int x = 0; x < 4; ++x) {
            const float* L = v3[x];
            const float* R = v3[x + 2];
            const float* D = dd[x];
            // W = L (*) R, truncated at degree 3
            const float w0 = L[0] * R[0];
            const float w1 = L[1] * R[0] + L[0] * R[1];
            const float w2 = L[2] * R[0] + L[1] * R[1] + L[0] * R[2];
            const float w3 = L[3] * R[0] + L[2] * R[1] + L[1] * R[2] + L[0] * R[3];
            // pmf2/pmf3 = coeffs of W (*) D
            const float pmf2 = w2 * D[0] + w1 * D[1] + w0 * D[2];
            const float pmf3 = w3 * D[0] + w2 * D[1] + w1 * D[2];
            rv4[x] = pmf3 + pmf2 * P[j + 1][x + 1];
        }
        // Safe non-temporal store (compiler-tracked): keeps the write-once
        // output stream from evicting the input out of L2.
        __builtin_nontemporal_store(
            rv4, reinterpret_cast<f32x4*>(o + (size_t)(r0 + j) * W + c0));
    }
}

extern "C" void kernel_launch(void* const* d_in, const int* in_sizes, int n_in,
                              void* d_out, int out_size, void* d_ws, size_t ws_size,
                              hipStream_t stream) {
    const float* in = (const float*)d_in[0];
    float* out = (float*)d_out;
    dim3 grid(32 * (H / RPT));   // 4096 blocks
    dim3 block(256);
    prob_conway_kernel<<<grid, block, 0, stream>>>(in, out);
}